// Round 14
// baseline (49.712 us; speedup 1.0000x reference)
//
#include <hip/hip_runtime.h>

#define QDIM 21
#define NDIM 1368
#define QN (QDIM * NDIM)
#define OUTSTRIDE 64000
#define XTOT (64 * QN)   // 1,838,592 x elements

typedef __attribute__((ext_vector_type(4))) float f32x4;
typedef __attribute__((ext_vector_type(8))) short bf16x8s;
typedef __attribute__((ext_vector_type(4))) unsigned int u32x4;

typedef __attribute__((address_space(1))) const unsigned int* gas_p;
typedef __attribute__((address_space(3))) unsigned int* las_p;

static __device__ __forceinline__ void gload16(const void* g, char* l) {
    __builtin_amdgcn_global_load_lds((gas_p)g, (las_p)(void*)l, 16, 0, 0);
}

// pack two f32 -> bf16x2 (round-half-up)
static __device__ __forceinline__ unsigned int pk2(float lo, float hi) {
    unsigned int a = __float_as_uint(lo) + 0x8000u;
    unsigned int b = __float_as_uint(hi) + 0x8000u;
    return __builtin_amdgcn_perm(b, a, 0x07060302);
}

static __device__ __forceinline__ bf16x8s pack8(f32x4 lo, f32x4 hi) {
    u32x4 p;
    p[0] = pk2(lo[0], lo[1]);
    p[1] = pk2(lo[2], lo[3]);
    p[2] = pk2(hi[0], hi[1]);
    p[3] = pk2(hi[2], hi[3]);
    return __builtin_bit_cast(bf16x8s, p);
}

// m204 bijective chunk swizzle within one filterbank's block range.
static __device__ __forceinline__ int chunk_swz(int idx, int n) {
    int xcd = idx & 7;
    int i   = idx >> 3;
    int q = n >> 3, r = n & 7;
    int base = (xcd < r) ? xcd * (q + 1) : r * (q + 1) + (xcd - r) * q;
    return base + i;
}

// x f32 -> bf16 (x is read ~27x by the GEMM; convert once).
__global__ __launch_bounds__(256)
void xcvt(const float* __restrict__ x, unsigned short* __restrict__ xb) {
    int i = (blockIdx.x * 256 + threadIdx.x) * 8;
    if (i >= XTOT) return;
    f32x4 lo = *(const f32x4*)(x + i);
    f32x4 hi = *(const f32x4*)(x + i + 4);
    *(u32x4*)(xb + i) = __builtin_bit_cast(u32x4, pack8(lo, hi));
}

// One 2-WAVE block computes C[0:64, n0:n0+32] for window position p.
// Both operands in a 3-stage gload_lds ring:
//   ABF16: A bf16 [64 rows x 64B] = 4 KB (pre-converted xb; no pack, linear,
//          structurally bank-balanced) + B f32 [32 rows x 128B] = 4 KB,
//          XOR-swizzled (seg^(row&7), pre-swizzled global source col).
//          Stage 8 KB, ring 24 KB -> 6 blocks/CU.  4 gloads/wave/stage.
//   else:  A f32 8 KB (R8 path, swizzled+pack) + B 4 KB; ring 36 KB. 6 gloads.
// Per tile t: vmcnt(4|6) [stage t landed, t+1 in flight]; s_barrier(2 waves);
// ds_read frags; pack B; 4 MFMA; STAGE(t+2) -> slot (t-1)%3.
template<int WLOG2, int NTX, int D, int P, int S, int K, bool ABF16>
__device__ __forceinline__ void fbk_body(const float* __restrict__ x,
                                         const unsigned short* __restrict__ xb,
                                         const float* __restrict__ W,
                                         float* __restrict__ out, int bid,
                                         char* lds) {
    constexpr int WWIN = 1 << WLOG2;
    constexpr int G = (K + 31) / 32;          // 42 / 21 / 11
    constexpr bool TAIL = (K % 32) != 0;      // fb0 only (K=336)
    constexpr int KREM = K & 31;              // 16 for fb0
    constexpr int FMAXC = (K - 4) & ~3;
    constexpr int ASTB = ABF16 ? 4096 : 8192;
    constexpr int STB  = ASTB + 4096;

    const int n0 = (bid % NTX) * 32;
    const int p  = bid / NTX;
    const int start = (p == P - 1) ? (NDIM - WWIN) : p * S;

    const int tid  = threadIdx.x;             // 0..127
    const int wid  = tid >> 6;                // 0..1
    const int lane = tid & 63;
    const int wm = wid * 32;                  // wave's output rows
    const int lr = lane & 15;
    const int hi = lane >> 4;
    const int kb = hi * 8;

    // ---- B staging (per wave: rows wid*16..+15 via 2 gloads, XOR-swizzled)
    const int lrow = lane >> 3;                   // 0..7
    const int g4   = ((lane & 7) ^ lrow) * 4;     // pre-swizzled source col (f32)
    const float* wb0 = W + (size_t)(p * D + n0 + wid * 16 + lrow) * K;
    const float* wb1 = wb0 + (size_t)8 * K;

    // ---- A staging
    // bf16: 2 insts/wave, rows wid*32 + {0,16} + (lane>>2), seg = lane&3
    const unsigned short* xr0 = xb + (size_t)(wid * 32 + (lane >> 2)) * QN + start;
    // f32: 4 insts/wave, rows wid*32 + {0,8,16,24} + lrow, swizzled col g4
    const float* xf0 = x + (size_t)(wid * 32 + lrow) * QN + start;

    auto STAGE = [&](int t, int sb) {
        if constexpr (ABF16) {
            int fa = t * 32 + (lane & 3) * 8;
            if constexpr (TAIL) fa = (fa > K - 8) ? (K - 8) : fa;  // garbage; zeroed at read
            int qa = fa >> WLOG2, ja = fa & (WWIN - 1);
            const unsigned short* ga = xr0 + qa * NDIM + ja;
            char* la = lds + sb + wid * 2048;
            gload16(ga, la);
            gload16(ga + (size_t)16 * QN, la + 1024);
        } else {
            int fa = t * 32 + g4;
            if constexpr (TAIL) fa = (fa > FMAXC) ? FMAXC : fa;
            int qa = fa >> WLOG2, ja = fa & (WWIN - 1);
            const float* ga = xf0 + qa * NDIM + ja;
            char* la = lds + sb + wid * 4096;
            gload16(ga,                       la);
            gload16(ga + (size_t) 8 * QN,     la + 1024);
            gload16(ga + (size_t)16 * QN,     la + 2048);
            gload16(ga + (size_t)24 * QN,     la + 3072);
        }
        int f = t * 32 + g4;
        if constexpr (TAIL) f = (f > FMAXC) ? FMAXC : f;
        char* lb = lds + sb + ASTB + wid * 2048;
        gload16(wb0 + f, lb);
        gload16(wb1 + f, lb + 1024);
    };

    // ---- fragment-read constants
    const int x7 = lr & 7;
    const int c0 = ((hi * 2)     ^ x7) * 16;
    const int c1 = ((hi * 2 + 1) ^ x7) * 16;
    const int oA0b = (wm + lr) * 64 + hi * 16;     // bf16 A
    const int oA1b = oA0b + 16 * 64;
    const int oA0f = (wm + lr) * 128;              // f32 A (swizzled)
    const int oA1f = (wm + 16 + lr) * 128;
    const int oB0 = ASTB + lr * 128;
    const int oB1 = ASTB + (16 + lr) * 128;

    f32x4 acc[2][2] = {};

    STAGE(0, 0);
    STAGE(1, STB);

    int cs = 0;
    #pragma unroll 1
    for (int t = 0; t < G; ++t) {
        if (t + 1 < G) {
            if constexpr (ABF16) asm volatile("s_waitcnt vmcnt(4)" ::: "memory");
            else                 asm volatile("s_waitcnt vmcnt(6)" ::: "memory");
        } else {
            asm volatile("s_waitcnt vmcnt(0)" ::: "memory");
        }
        __builtin_amdgcn_sched_barrier(0);
        __builtin_amdgcn_s_barrier();
        __builtin_amdgcn_sched_barrier(0);

        const char* sb = lds + cs;
        bf16x8s A0, A1;
        if constexpr (ABF16) {
            A0 = *(const bf16x8s*)(sb + oA0b);
            A1 = *(const bf16x8s*)(sb + oA1b);
            if constexpr (TAIL) {
                if (t == G - 1 && kb >= KREM) {
                    A0 = __builtin_bit_cast(bf16x8s, (u32x4){0u, 0u, 0u, 0u});
                    A1 = A0;
                }
            }
        } else {
            f32x4 a00 = *(const f32x4*)(sb + oA0f + c0);
            f32x4 a01 = *(const f32x4*)(sb + oA0f + c1);
            f32x4 a10 = *(const f32x4*)(sb + oA1f + c0);
            f32x4 a11 = *(const f32x4*)(sb + oA1f + c1);
            if constexpr (TAIL) {
                if (t == G - 1 && kb >= KREM) {
                    f32x4 z = {0.f, 0.f, 0.f, 0.f};
                    a00 = z; a01 = z; a10 = z; a11 = z;
                }
            }
            A0 = pack8(a00, a01);
            A1 = pack8(a10, a11);
        }
        f32x4 b00 = *(const f32x4*)(sb + oB0 + c0);
        f32x4 b01 = *(const f32x4*)(sb + oB0 + c1);
        f32x4 b10 = *(const f32x4*)(sb + oB1 + c0);
        f32x4 b11 = *(const f32x4*)(sb + oB1 + c1);
        bf16x8s B0 = pack8(b00, b01);
        bf16x8s B1 = pack8(b10, b11);

        acc[0][0] = __builtin_amdgcn_mfma_f32_16x16x32_bf16(A0, B0, acc[0][0], 0, 0, 0);
        acc[0][1] = __builtin_amdgcn_mfma_f32_16x16x32_bf16(A0, B1, acc[0][1], 0, 0, 0);
        acc[1][0] = __builtin_amdgcn_mfma_f32_16x16x32_bf16(A1, B0, acc[1][0], 0, 0, 0);
        acc[1][1] = __builtin_amdgcn_mfma_f32_16x16x32_bf16(A1, B1, acc[1][1], 0, 0, 0);

        __builtin_amdgcn_sched_barrier(0);
        if (t + 2 < G) {
            int pb = (cs == 0) ? 2 * STB : cs - STB;   // slot (t+2)%3 == (t-1)%3
            STAGE(t + 2, pb);
        }
        cs = (cs == 2 * STB) ? 0 : cs + STB;
    }

    // epilogue: C/D layout col = lane&15, row = (lane>>4)*4 + r
    const int colbase = p * D + n0;
    #pragma unroll
    for (int mi = 0; mi < 2; ++mi) {
        #pragma unroll
        for (int ni = 0; ni < 2; ++ni) {
            int col = colbase + ni * 16 + lr;
            int rbase = wm + mi * 16 + hi * 4;
            #pragma unroll
            for (int r = 0; r < 4; ++r) {
                out[(size_t)(rbase + r) * OUTSTRIDE + col] = acc[mi][ni][r];
            }
        }
    }
}

// 2000 blocks x 128 threads, fb2 first (tail packing), per-segment chunk
// swizzle (R8 locality + R12 balance lesson). BF=true: 24 KB LDS -> 6
// blocks/CU, 12 waves in 6 INDEPENDENT 2-wave barrier groups per CU.
template<bool BF>
__global__ __launch_bounds__(128, 3)
void fbk_fused(const float* __restrict__ x,  const unsigned short* __restrict__ xb,
               const float* __restrict__ w0, const float* __restrict__ w1,
               const float* __restrict__ w2, float* __restrict__ out) {
    constexpr int STB = BF ? 8192 : 12288;
    __shared__ __align__(16) char lds[3 * STB];
    const int pb = blockIdx.x;
    if (pb < 656) {
        // fb2: w=64, s=16, d=256, P=82, K=1344, 8 n-tiles of 32
        fbk_body<6, 8, 256, 82, 16, 1344, BF>(x, xb, w2, out + 43008, chunk_swz(pb, 656), lds);
    } else if (pb < 1324) {
        // fb1: w=32, s=8, d=128, P=167, K=672, 4 n-tiles of 32
        fbk_body<5, 4, 128, 167, 8, 672, BF>(x, xb, w1, out + 21632, chunk_swz(pb - 656, 668), lds);
    } else {
        // fb0: w=16, s=4, d=64, P=338, K=336, 2 n-tiles of 32
        fbk_body<4, 2, 64, 338, 4, 336, BF>(x, xb, w0, out, chunk_swz(pb - 1324, 676), lds);
    }
}

extern "C" void kernel_launch(void* const* d_in, const int* in_sizes, int n_in,
                              void* d_out, int out_size, void* d_ws, size_t ws_size,
                              hipStream_t stream) {
    const float* x  = (const float*)d_in[0];
    const float* w0 = (const float*)d_in[1];
    const float* w1 = (const float*)d_in[2];
    const float* w2 = (const float*)d_in[3];
    float* out = (float*)d_out;
    constexpr size_t XBF_BYTES = (size_t)XTOT * 2;   // 3.68 MB
    if (ws_size >= XBF_BYTES) {
        unsigned short* xbuf = (unsigned short*)d_ws;
        xcvt<<<dim3((XTOT / 8 + 255) / 256), 256, 0, stream>>>(x, xbuf);
        fbk_fused<true><<<dim3(2000), 128, 0, stream>>>(x, xbuf, w0, w1, w2, out);
    } else {
        fbk_fused<false><<<dim3(2000), 128, 0, stream>>>(x, nullptr, w0, w1, w2, out);
    }
}

// Round 15
// 45.339 us; speedup vs baseline: 1.0964x; 1.0964x over previous
//
#include <hip/hip_runtime.h>

#define QDIM 21
#define NDIM 1368
#define QN (QDIM * NDIM)
#define OUTSTRIDE 64000
#define XTOT (64 * QN)   // 1,838,592 x elements

typedef __attribute__((ext_vector_type(4))) float f32x4;
typedef __attribute__((ext_vector_type(8))) short bf16x8s;
typedef __attribute__((ext_vector_type(4))) unsigned int u32x4;

typedef __attribute__((address_space(1))) const unsigned int* gas_p;
typedef __attribute__((address_space(3))) unsigned int* las_p;

static __device__ __forceinline__ void gload16(const void* g, char* l) {
    __builtin_amdgcn_global_load_lds((gas_p)g, (las_p)(void*)l, 16, 0, 0);
}

// pack two f32 -> bf16x2 (round-half-up)
static __device__ __forceinline__ unsigned int pk2(float lo, float hi) {
    unsigned int a = __float_as_uint(lo) + 0x8000u;
    unsigned int b = __float_as_uint(hi) + 0x8000u;
    return __builtin_amdgcn_perm(b, a, 0x07060302);
}

static __device__ __forceinline__ bf16x8s pack8(f32x4 lo, f32x4 hi) {
    u32x4 p;
    p[0] = pk2(lo[0], lo[1]);
    p[1] = pk2(lo[2], lo[3]);
    p[2] = pk2(hi[0], hi[1]);
    p[3] = pk2(hi[2], hi[3]);
    return __builtin_bit_cast(bf16x8s, p);
}

// m204 bijective chunk swizzle within one filterbank's block range (R8).
static __device__ __forceinline__ int chunk_swz(int idx, int n) {
    int xcd = idx & 7;
    int i   = idx >> 3;
    int q = n >> 3, r = n & 7;
    int base = (xcd < r) ? xcd * (q + 1) : r * (q + 1) + (xcd - r) * q;
    return base + i;
}

// x f32 -> bf16 (x is read ~27x by the GEMM; convert once).
__global__ __launch_bounds__(256)
void xcvt(const float* __restrict__ x, unsigned short* __restrict__ xb) {
    int i = (blockIdx.x * 256 + threadIdx.x) * 8;
    if (i >= XTOT) return;
    f32x4 lo = *(const f32x4*)(x + i);
    f32x4 hi = *(const f32x4*)(x + i + 4);
    *(u32x4*)(xb + i) = __builtin_bit_cast(u32x4, pack8(lo, hi));
}

// One 4-wave block computes C[0:64, n0:n0+64] for window position p.
// R8 champion structure; only A's representation changed:
//   ABF16: A bf16 [64 rows x 64B] = 4 KB, linear (1 gload/wave: wave w rows
//          16w..16w+15, lane l -> row 16w+(l>>2), seg l&3; dest sbase+1024w+16l
//          == row-major). No pack; direct bf16x8s frag reads.
//   else:  A f32 8 KB (R8 exact: 2 gloads/wave, XOR-swizzle, pack on read).
// B (both): f32 8 KB, 2 gloads/wave, XOR swizzle seg^(row&7) via pre-swizzled
//   global col; pack8 on read.
// Ring: 3 stages, counted vmcnt(3|4) at phase top (t+1 stays in flight),
// vmcnt(0) only at last tile; STAGE(t+2) -> slot (t-1)%3 after MFMA.
template<int WLOG2, int NTX, int D, int P, int S, int K, bool ABF16>
__device__ __forceinline__ void fbk_body(const float* __restrict__ x,
                                         const unsigned short* __restrict__ xb,
                                         const float* __restrict__ W,
                                         float* __restrict__ out, int bid,
                                         char* ldsraw) {
    constexpr int WWIN = 1 << WLOG2;
    constexpr int G = (K + 31) / 32;          // 42 / 21 / 11
    constexpr bool TAIL = (K % 32) != 0;      // fb0 only (K=336)
    constexpr int KREM = K & 31;              // 16 for fb0
    constexpr int FMAXC = (K - 4) & ~3;       // B tail clamp (f32 segs)
    constexpr int ASTB = ABF16 ? 4096 : 8192;
    constexpr int STB  = ASTB + 8192;         // 12288 / 16384

    const int n0 = (bid % NTX) * 64;
    const int p  = bid / NTX;
    const int start = (p == P - 1) ? (NDIM - WWIN) : p * S;

    const int tid  = threadIdx.x;
    const int wid  = tid >> 6;
    const int lane = tid & 63;
    const int wm = (wid >> 1) * 32;
    const int wn = (wid & 1) * 32;
    const int lr = lane & 15;
    const int hi = lane >> 4;
    const int kb = hi * 8;

    // ---- B staging constants (R8 exact)
    const int lrow = lane >> 3;                   // 0..7
    const int g4   = ((lane & 7) ^ lrow) * 4;     // pre-swizzled source col (f32)
    const float* Wp  = W + (size_t)(p * D + n0) * K;
    const float* wb0 = Wp + (size_t)(16 * wid + lrow) * K;
    const float* wb1 = wb0 + (size_t)8 * K;
    const int wB = 2048 * wid;

    // ---- A staging constants
    // bf16: wave w stages rows 16w..16w+15; lane -> row 16w+(l>>2), seg l&3
    const unsigned short* xr0 = xb + (size_t)(16 * wid + (lane >> 2)) * QN + start;
    // f32 fallback (R8): rows 16w+lrow, +8; swizzled col g4
    const float* xf0 = x + (size_t)(16 * wid + lrow) * QN + start;

    auto STAGE = [&](int t, int sbase) {
        if constexpr (ABF16) {
            int fa = t * 32 + (lane & 3) * 8;     // bf16 elem index
            if constexpr (TAIL) fa = (fa > K - 8) ? (K - 8) : fa;  // garbage; A zeroed at read
            int qa = fa >> WLOG2, ja = fa & (WWIN - 1);
            gload16(xr0 + qa * NDIM + ja, ldsraw + sbase + 1024 * wid);
        } else {
            int fa = t * 32 + g4;
            if constexpr (TAIL) fa = (fa > FMAXC) ? FMAXC : fa;
            int qa = fa >> WLOG2, ja = fa & (WWIN - 1);
            const float* ga = xf0 + qa * NDIM + ja;
            char* la = ldsraw + sbase + 2048 * wid;
            gload16(ga, la);
            gload16(ga + (size_t)8 * QN, la + 1024);
        }
        int f = t * 32 + g4;
        if constexpr (TAIL) f = (f > FMAXC) ? FMAXC : f;
        char* lb = ldsraw + sbase + ASTB + wB;
        gload16(wb0 + f, lb);
        gload16(wb1 + f, lb + 1024);
    };

    // ---- fragment-read constants
    const int x7 = lr & 7;
    const int c0 = ((hi * 2)     ^ x7) * 16;
    const int c1 = ((hi * 2 + 1) ^ x7) * 16;
    const int oA0b = (wm + lr) * 64 + hi * 16;    // bf16 A, row-major
    const int oA1b = oA0b + 1024;                 // +16 rows
    const int oA0f = (wm + lr) * 128;             // f32 A (swizzled)
    const int oA1f = (wm + 16 + lr) * 128;
    const int oB0 = ASTB + (wn + lr) * 128;
    const int oB1 = ASTB + (wn + 16 + lr) * 128;

    f32x4 acc[2][2] = {};

    STAGE(0, 0);
    STAGE(1, STB);

    int cs = 0;   // byte base of current tile's stage
    #pragma unroll 1
    for (int t = 0; t < G; ++t) {
        if (t + 1 < G) {
            if constexpr (ABF16) asm volatile("s_waitcnt vmcnt(3)" ::: "memory");
            else                 asm volatile("s_waitcnt vmcnt(4)" ::: "memory");
        } else {
            asm volatile("s_waitcnt vmcnt(0)" ::: "memory");
        }
        __builtin_amdgcn_sched_barrier(0);
        __builtin_amdgcn_s_barrier();
        __builtin_amdgcn_sched_barrier(0);

        const char* sb = ldsraw + cs;
        bf16x8s A0, A1;
        if constexpr (ABF16) {
            A0 = *(const bf16x8s*)(sb + oA0b);
            A1 = *(const bf16x8s*)(sb + oA1b);
            if constexpr (TAIL) {
                if (t == G - 1 && kb >= KREM) {
                    A0 = __builtin_bit_cast(bf16x8s, (u32x4){0u, 0u, 0u, 0u});
                    A1 = A0;
                }
            }
        } else {
            f32x4 a00 = *(const f32x4*)(sb + oA0f + c0);
            f32x4 a01 = *(const f32x4*)(sb + oA0f + c1);
            f32x4 a10 = *(const f32x4*)(sb + oA1f + c0);
            f32x4 a11 = *(const f32x4*)(sb + oA1f + c1);
            if constexpr (TAIL) {
                if (t == G - 1 && kb >= KREM) {
                    f32x4 z = {0.f, 0.f, 0.f, 0.f};
                    a00 = z; a01 = z; a10 = z; a11 = z;
                }
            }
            A0 = pack8(a00, a01);
            A1 = pack8(a10, a11);
        }
        f32x4 b00 = *(const f32x4*)(sb + oB0 + c0);
        f32x4 b01 = *(const f32x4*)(sb + oB0 + c1);
        f32x4 b10 = *(const f32x4*)(sb + oB1 + c0);
        f32x4 b11 = *(const f32x4*)(sb + oB1 + c1);
        bf16x8s B0 = pack8(b00, b01);
        bf16x8s B1 = pack8(b10, b11);

        acc[0][0] = __builtin_amdgcn_mfma_f32_16x16x32_bf16(A0, B0, acc[0][0], 0, 0, 0);
        acc[0][1] = __builtin_amdgcn_mfma_f32_16x16x32_bf16(A0, B1, acc[0][1], 0, 0, 0);
        acc[1][0] = __builtin_amdgcn_mfma_f32_16x16x32_bf16(A1, B0, acc[1][0], 0, 0, 0);
        acc[1][1] = __builtin_amdgcn_mfma_f32_16x16x32_bf16(A1, B1, acc[1][1], 0, 0, 0);

        __builtin_amdgcn_sched_barrier(0);
        if (t + 2 < G) {
            int pb = (cs == 0) ? 2 * STB : cs - STB;   // slot (t+2)%3 == (t-1)%3
            STAGE(t + 2, pb);
        }
        cs = (cs == 2 * STB) ? 0 : cs + STB;
    }

    // epilogue: C/D layout col = lane&15, row = (lane>>4)*4 + r
    const int colbase = p * D + n0;
    #pragma unroll
    for (int mi = 0; mi < 2; ++mi) {
        #pragma unroll
        for (int ni = 0; ni < 2; ++ni) {
            int col = colbase + wn + ni * 16 + lr;
            int rbase = wm + mi * 16 + hi * 4;
            #pragma unroll
            for (int r = 0; r < 4; ++r) {
                out[(size_t)(rbase + r) * OUTSTRIDE + col] = acc[mi][ni][r];
            }
        }
    }
}

// 1000 blocks, fb2 first (tail packing), per-segment chunk swizzle (R8).
// BF=true: 36 KB LDS -> 4 blocks/CU, uniform counted ring for ALL segments.
template<bool BF>
__global__ __launch_bounds__(256, 4)
void fbk_fused(const float* __restrict__ x,  const unsigned short* __restrict__ xb,
               const float* __restrict__ w0, const float* __restrict__ w1,
               const float* __restrict__ w2, float* __restrict__ out) {
    constexpr int STB = BF ? 12288 : 16384;
    __shared__ __align__(16) char ldsraw[3 * STB];
    const int pb = blockIdx.x;
    if (pb < 328) {
        // fb2: w=64, s=16, d=256, P=82, K=1344, 4 n-tiles
        fbk_body<6, 4, 256, 82, 16, 1344, BF>(x, xb, w2, out + 43008, chunk_swz(pb, 328), ldsraw);
    } else if (pb < 662) {
        // fb1: w=32, s=8, d=128, P=167, K=672, 2 n-tiles
        fbk_body<5, 2, 128, 167, 8, 672, BF>(x, xb, w1, out + 21632, chunk_swz(pb - 328, 334), ldsraw);
    } else {
        // fb0: w=16, s=4, d=64, P=338, K=336, 1 n-tile
        fbk_body<4, 1, 64, 338, 4, 336, BF>(x, xb, w0, out, chunk_swz(pb - 662, 338), ldsraw);
    }
}

extern "C" void kernel_launch(void* const* d_in, const int* in_sizes, int n_in,
                              void* d_out, int out_size, void* d_ws, size_t ws_size,
                              hipStream_t stream) {
    const float* x  = (const float*)d_in[0];
    const float* w0 = (const float*)d_in[1];
    const float* w1 = (const float*)d_in[2];
    const float* w2 = (const float*)d_in[3];
    float* out = (float*)d_out;
    constexpr size_t XBF_BYTES = (size_t)XTOT * 2;   // 3.68 MB
    if (ws_size >= XBF_BYTES) {
        unsigned short* xbuf = (unsigned short*)d_ws;
        xcvt<<<dim3((XTOT / 8 + 255) / 256), 256, 0, stream>>>(x, xbuf);
        fbk_fused<true><<<dim3(1000), 256, 0, stream>>>(x, xbuf, w0, w1, w2, out);
    } else {
        fbk_fused<false><<<dim3(1000), 256, 0, stream>>>(x, nullptr, w0, w1, w2, out);
    }
}

// Round 16
// 44.360 us; speedup vs baseline: 1.1206x; 1.0221x over previous
//
#include <hip/hip_runtime.h>

#define QDIM 21
#define NDIM 1368
#define QN (QDIM * NDIM)
#define OUTSTRIDE 64000
#define XTOT (64 * QN)   // 1,838,592 x elements

typedef __attribute__((ext_vector_type(4))) float f32x4;
typedef __attribute__((ext_vector_type(8))) short bf16x8s;
typedef __attribute__((ext_vector_type(4))) unsigned int u32x4;

typedef __attribute__((address_space(1))) const unsigned int* gas_p;
typedef __attribute__((address_space(3))) unsigned int* las_p;

static __device__ __forceinline__ void gload16(const void* g, char* l) {
    __builtin_amdgcn_global_load_lds((gas_p)g, (las_p)(void*)l, 16, 0, 0);
}

// pack two f32 -> bf16x2 (round-half-up)
static __device__ __forceinline__ unsigned int pk2(float lo, float hi) {
    unsigned int a = __float_as_uint(lo) + 0x8000u;
    unsigned int b = __float_as_uint(hi) + 0x8000u;
    return __builtin_amdgcn_perm(b, a, 0x07060302);
}

static __device__ __forceinline__ bf16x8s pack8(f32x4 lo, f32x4 hi) {
    u32x4 p;
    p[0] = pk2(lo[0], lo[1]);
    p[1] = pk2(lo[2], lo[3]);
    p[2] = pk2(hi[0], hi[1]);
    p[3] = pk2(hi[2], hi[3]);
    return __builtin_bit_cast(bf16x8s, p);
}

// m204 bijective chunk swizzle within one filterbank's block range (R8).
static __device__ __forceinline__ int chunk_swz(int idx, int n) {
    int xcd = idx & 7;
    int i   = idx >> 3;
    int q = n >> 3, r = n & 7;
    int base = (xcd < r) ? xcd * (q + 1) : r * (q + 1) + (xcd - r) * q;
    return base + i;
}

// x f32 -> bf16 (x is read ~27x by the GEMM; convert once).
__global__ __launch_bounds__(256)
void xcvt(const float* __restrict__ x, unsigned short* __restrict__ xb) {
    int i = (blockIdx.x * 256 + threadIdx.x) * 8;
    if (i >= XTOT) return;
    f32x4 lo = *(const f32x4*)(x + i);
    f32x4 hi = *(const f32x4*)(x + i + 4);
    *(u32x4*)(xb + i) = __builtin_bit_cast(u32x4, pack8(lo, hi));
}

// One 4-wave block computes C[0:64, n0:n0+64] for window position p.
// BK=64 (2 k-substeps, 8 MFMA/wave/phase) -> HALF the phases of R8.
// Stage (24 KB): A bf16 [64][128B] (from pre-converted xb; XOR seg^(row&7))
//              + B f32  [64][256B] (XOR seg^(row&15)); both 2-way-free reads.
// 2-stage ping-pong (48 KB, 3 blocks/CU). Per phase t:
//   vmcnt(0)   — only stage t outstanding (issued one full phase earlier)
//   s_barrier  — certifies all waves' stage-t loads AND phase t-1 reads
//   STAGE(t+1) — into buffer (t+1)&1 (just certified free)
//   12x ds_read_b128 ; B pack ; 8x MFMA
template<int WLOG2, int NTX, int D, int P, int S, int K>
__device__ __forceinline__ void fbk_body(const unsigned short* __restrict__ xb,
                                         const float* __restrict__ W,
                                         float* __restrict__ out, int bid,
                                         char* lds) {
    constexpr int WWIN = 1 << WLOG2;
    constexpr int G = (K + 63) / 64;          // 21 / 11 / 6
    constexpr bool TAIL = (K % 64) != 0;      // fb1 (32), fb0 (16)
    constexpr int KREM = K % 64;
    constexpr int STB = 24576;

    const int n0 = (bid % NTX) * 64;
    const int p  = bid / NTX;
    const int start = (p == P - 1) ? (NDIM - WWIN) : p * S;

    const int tid  = threadIdx.x;
    const int wid  = tid >> 6;
    const int lane = tid & 63;
    const int wm = (wid >> 1) * 32;
    const int wn = (wid & 1) * 32;
    const int lr = lane & 15;
    const int hi = lane >> 4;
    const int kb = hi * 8;

    // ---- A staging: wave stages rows 16wid..+15; 2 gloads (8 rows each).
    // lane -> row 16wid + 8g + (lane>>3), seg (lane&7)^(row&7) (pre-swizzled).
    const int ar   = lane >> 3;                       // 0..7
    const int aseg = ((lane & 7) ^ ar) * 8;           // bf16 elem offset
    const unsigned short* xrA = xb + (size_t)(16 * wid + ar) * QN + start;

    // ---- B staging: wave stages rows 16wid..+15; 4 gloads (4 rows each).
    // lane -> row 16wid + 4g + (lane>>4), seg (lane&15)^(4g+br) (pre-swizzled).
    const int br = lane >> 4;                         // 0..3
    const float* wbase = W + (size_t)(p * D + n0 + 16 * wid) * K;

    auto STAGE = [&](int t, int sbase) {
        {
            int fa = t * 64 + aseg;
            if constexpr (TAIL) fa = (fa > K - 8) ? (K - 8) : fa;  // garbage; A zeroed at read
            int q = fa >> WLOG2, j = fa & (WWIN - 1);
            const unsigned short* ga = xrA + q * NDIM + j;
            char* la = lds + sbase + wid * 2048;
            gload16(ga, la);
            gload16(ga + (size_t)8 * QN, la + 1024);
        }
        #pragma unroll
        for (int g = 0; g < 4; ++g) {
            int srow = 4 * g + br;                     // row&15 within half-tile
            int scol = ((lane & 15) ^ srow) * 4;       // f32 col, pre-swizzled
            int fb = t * 64 + scol;
            if constexpr (TAIL) fb = (fb > K - 4) ? (K - 4) : fb;  // garbage; A=0 covers
            gload16(wbase + (size_t)srow * K + fb,
                    lds + sbase + 8192 + wid * 4096 + g * 1024);
        }
    };

    // ---- fragment-read offsets (both XOR-matched to staging; 2-way-free)
    const int oA0 = (wm + lr) * 128;                   // A row stride 128B
    const int oA1 = oA0 + 2048;                        // +16 rows
    const int oB0 = 8192 + (wn + lr) * 256;            // B row stride 256B
    const int oB1 = oB0 + 4096;                        // +16 rows
    int cA[2], cB[2][2];
    #pragma unroll
    for (int kk = 0; kk < 2; ++kk) {
        cA[kk]    = ((kk * 4 + hi) ^ (lr & 7)) * 16;
        cB[kk][0] = ((kk * 8 + hi * 2)     ^ lr) * 16;
        cB[kk][1] = ((kk * 8 + hi * 2 + 1) ^ lr) * 16;
    }

    f32x4 acc[2][2] = {};

    STAGE(0, 0);

    #pragma unroll 1
    for (int t = 0; t < G; ++t) {
        asm volatile("s_waitcnt vmcnt(0)" ::: "memory");   // stage t landed (mine)
        __builtin_amdgcn_sched_barrier(0);
        __builtin_amdgcn_s_barrier();                      // everyone's landed; t-1 reads done
        __builtin_amdgcn_sched_barrier(0);

        if (t + 1 < G) STAGE(t + 1, (t & 1) ? 0 : STB);    // buf (t+1)&1
        __builtin_amdgcn_sched_barrier(0);

        const char* sb = lds + ((t & 1) ? STB : 0);
        #pragma unroll
        for (int kk = 0; kk < 2; ++kk) {
            bf16x8s A0 = *(const bf16x8s*)(sb + oA0 + cA[kk]);
            bf16x8s A1 = *(const bf16x8s*)(sb + oA1 + cA[kk]);
            if constexpr (TAIL) {
                if (t == G - 1 && kk * 32 + kb >= KREM) {
                    A0 = __builtin_bit_cast(bf16x8s, (u32x4){0u, 0u, 0u, 0u});
                    A1 = A0;
                }
            }
            f32x4 b00 = *(const f32x4*)(sb + oB0 + cB[kk][0]);
            f32x4 b01 = *(const f32x4*)(sb + oB0 + cB[kk][1]);
            f32x4 b10 = *(const f32x4*)(sb + oB1 + cB[kk][0]);
            f32x4 b11 = *(const f32x4*)(sb + oB1 + cB[kk][1]);
            bf16x8s B0 = pack8(b00, b01);
            bf16x8s B1 = pack8(b10, b11);

            acc[0][0] = __builtin_amdgcn_mfma_f32_16x16x32_bf16(A0, B0, acc[0][0], 0, 0, 0);
            acc[0][1] = __builtin_amdgcn_mfma_f32_16x16x32_bf16(A0, B1, acc[0][1], 0, 0, 0);
            acc[1][0] = __builtin_amdgcn_mfma_f32_16x16x32_bf16(A1, B0, acc[1][0], 0, 0, 0);
            acc[1][1] = __builtin_amdgcn_mfma_f32_16x16x32_bf16(A1, B1, acc[1][1], 0, 0, 0);
        }
    }

    // epilogue: C/D layout col = lane&15, row = (lane>>4)*4 + r
    const int colbase = p * D + n0;
    #pragma unroll
    for (int mi = 0; mi < 2; ++mi) {
        #pragma unroll
        for (int ni = 0; ni < 2; ++ni) {
            int col = colbase + wn + ni * 16 + lr;
            int rbase = wm + mi * 16 + hi * 4;
            #pragma unroll
            for (int r = 0; r < 4; ++r) {
                out[(size_t)(rbase + r) * OUTSTRIDE + col] = acc[mi][ni][r];
            }
        }
    }
}

// 1000 blocks, fb2 first (tail packing), per-segment chunk swizzle (R8).
// 48 KB LDS -> 3 blocks/CU.
__global__ __launch_bounds__(256, 3)
void fbk_fused(const unsigned short* __restrict__ xb,
               const float* __restrict__ w0, const float* __restrict__ w1,
               const float* __restrict__ w2, float* __restrict__ out) {
    __shared__ __align__(16) char lds[2 * 24576];
    const int pb = blockIdx.x;
    if (pb < 328) {
        // fb2: w=64, s=16, d=256, P=82, K=1344 (21 full phases, no tail)
        fbk_body<6, 4, 256, 82, 16, 1344>(xb, w2, out + 43008, chunk_swz(pb, 328), lds);
    } else if (pb < 662) {
        // fb1: w=32, s=8, d=128, P=167, K=672 (G=11, tail 32)
        fbk_body<5, 2, 128, 167, 8, 672>(xb, w1, out + 21632, chunk_swz(pb - 328, 334), lds);
    } else {
        // fb0: w=16, s=4, d=64, P=338, K=336 (G=6, tail 16)
        fbk_body<4, 1, 64, 338, 4, 336>(xb, w0, out, chunk_swz(pb - 662, 338), lds);
    }
}

extern "C" void kernel_launch(void* const* d_in, const int* in_sizes, int n_in,
                              void* d_out, int out_size, void* d_ws, size_t ws_size,
                              hipStream_t stream) {
    const float* x  = (const float*)d_in[0];
    const float* w0 = (const float*)d_in[1];
    const float* w1 = (const float*)d_in[2];
    const float* w2 = (const float*)d_in[3];
    float* out = (float*)d_out;
    unsigned short* xbuf = (unsigned short*)d_ws;   // 3.68 MB (ws verified >= this in R13-R15)
    xcvt<<<dim3((XTOT / 8 + 255) / 256), 256, 0, stream>>>(x, xbuf);
    fbk_fused<<<dim3(1000), 256, 0, stream>>>(xbuf, w0, w1, w2, out);
}